// Round 20
// baseline (174.826 us; speedup 1.0000x reference)
//
#include <hip/hip_runtime.h>
#include <hip/hip_cooperative_groups.h>

namespace cg = cooperative_groups;

#define NUM_NODES 100000
#define INPUT_DIM 256
#define NUM_BAGS  2048
#define BAG_SIZE  64
#define N_EDGES   3200000
#define NQUAD     (N_EDGES / 4)   // 800000
#define P_PART    8
#define NPP       12500           // 50 KB static LDS
#define NSLICE    32
#define QPS       (NQUAD / NSLICE)   // 25000
#define NBLK      256
#define REDB      25              // reduce blocks; 25*1024 = 25600 >= 25000

typedef unsigned int u32;
typedef float f4 __attribute__((ext_vector_type(4)));

// Single cooperative kernel: pack -> hist -> (reduce || gemv) -> bag.
// Eliminates 4 kernel-launch drain/ramp boundaries (~17 us residual at R13).
__global__ void __launch_bounds__(1024, 1)
fused_all(const int* __restrict__ edge_src, const int* __restrict__ edge_nbr,
          const float* __restrict__ nw, const int* __restrict__ bags,
          const float* __restrict__ alpha, const float* __restrict__ x,
          const float* __restrict__ theta,
          u32* __restrict__ packed, float* __restrict__ rep,
          float* __restrict__ nbr_sum, float* __restrict__ h,
          float* __restrict__ out) {
    cg::grid_group grid = cg::this_grid();
    __shared__ float hist[NPP];

    const int blk = blockIdx.x;
    const int tid = threadIdx.x;

    // ---- Phase 1: pack (src<<15 | bf15(nw[nbr])), grid-stride ----
    for (int q = blk * 1024 + tid; q < NQUAD; q += NBLK * 1024) {
        const int4 s4 = ((const int4*)edge_src)[q];
        const int4 n4 = ((const int4*)edge_nbr)[q];
#define PACK(S, N)  (((u32)(S) << 15) |                                     \
                     (((__float_as_uint(nw[(N)]) + 0x8000u) >> 16) & 0x7FFFu))
        uint4 o;
        o.x = PACK(s4.x, n4.x);
        o.y = PACK(s4.y, n4.y);
        o.z = PACK(s4.z, n4.z);
        o.w = PACK(s4.w, n4.w);
#undef PACK
        ((uint4*)packed)[q] = o;
    }
    grid.sync();

    // ---- Phase 2: P=8 partitioned LDS hist; exactly 256 (p,b) units ----
    {
        const int r    = blk & 7;
        const int p    = (blk >> 3) & 7;
        const int b    = r | ((blk >> 6) << 3);   // 0..31
        const int base = p * NPP;

        for (int j = tid; j < NPP / 4; j += 1024)
            ((f4*)hist)[j] = (f4){0.f, 0.f, 0.f, 0.f};
        __syncthreads();

        const int lo = b * QPS;
#define EDGE(W)                                                          \
        {                                                                \
            const u32 rel = ((W) >> 15) - (u32)base;                     \
            if (rel < (u32)NPP)                                          \
                atomicAdd(&hist[rel],                                    \
                          __uint_as_float(((W) & 0x7FFFu) << 16));       \
        }
        for (int q = lo + tid; q < lo + QPS; q += 1024) {
            const uint4 a = ((const uint4*)packed)[q];
            EDGE(a.x) EDGE(a.y) EDGE(a.z) EDGE(a.w)
        }
#undef EDGE
        __syncthreads();

        float* dst = rep + (size_t)b * NUM_NODES + base;
        for (int j = tid; j < NPP / 4; j += 1024) {
            const f4 v = ((const f4*)hist)[j];
            __builtin_nontemporal_store(v, &((f4*)dst)[j]);
        }
    }
    grid.sync();

    // ---- Phase 3: blocks [0,REDB) reduce rep -> nbr_sum; rest dense GEMV ----
    if (blk < REDB) {
        for (int i = blk * 1024 + tid; i < NUM_NODES / 4; i += REDB * 1024) {
            float4 a = make_float4(0.f, 0.f, 0.f, 0.f);
            #pragma unroll 8
            for (int r = 0; r < NSLICE; ++r) {
                const float4 v = ((const float4*)(rep + (size_t)r * NUM_NODES))[i];
                a.x += v.x; a.y += v.y; a.z += v.z; a.w += v.w;
            }
            float4 o;
            o.x = a.x > 0.f ? a.x : 1.0f;
            o.y = a.y > 0.f ? a.y : 1.0f;
            o.z = a.z > 0.f ? a.z : 1.0f;
            o.w = a.w > 0.f ? a.w : 1.0f;
            ((float4*)nbr_sum)[i] = o;
        }
    } else {
        const int lane = tid & 63;
        const int wv   = tid >> 6;
        const float4 tw = *reinterpret_cast<const float4*>(&theta[lane * 4]);
        for (int row = (blk - REDB) * 16 + wv; row < NUM_NODES;
             row += (NBLK - REDB) * 16) {
            const float4 xv =
                *reinterpret_cast<const float4*>(&x[(size_t)row * INPUT_DIM + lane * 4]);
            float d = xv.x * tw.x + xv.y * tw.y + xv.z * tw.z + xv.w * tw.w;
            #pragma unroll
            for (int off = 32; off >= 1; off >>= 1)
                d += __shfl_xor(d, off);
            if (lane == 0) h[row] = d;
        }
    }
    grid.sync();

    // ---- Phase 4: one wave per bag ----
    {
        const int gw   = blk * 16 + (tid >> 6);   // global wave id, 4096 total
        const int lane = tid & 63;
        if (gw < NUM_BAGS) {
            const int idx = bags[gw * BAG_SIZE + lane];
            float v = h[idx] * nbr_sum[idx] * alpha[gw * BAG_SIZE + lane];
            #pragma unroll
            for (int off = 32; off >= 1; off >>= 1)
                v += __shfl_xor(v, off);
            if (lane == 0) out[gw] = v;
        }
    }
}

// ---------------------------------------------------------------------------
// Fallback path = R13 (proven 66.9 us): 5 separate kernels.
__global__ void __launch_bounds__(256)
pack_edges(const int* __restrict__ edge_src, const int* __restrict__ edge_nbr,
           const float* __restrict__ nw, u32* __restrict__ packed) {
    const int q = blockIdx.x * 256 + threadIdx.x;
    const int4 s4 = ((const int4*)edge_src)[q];
    const int4 n4 = ((const int4*)edge_nbr)[q];
#define PACK(S, N)  (((u32)(S) << 15) |                                     \
                     (((__float_as_uint(nw[(N)]) + 0x8000u) >> 16) & 0x7FFFu))
    uint4 o;
    o.x = PACK(s4.x, n4.x);
    o.y = PACK(s4.y, n4.y);
    o.z = PACK(s4.z, n4.z);
    o.w = PACK(s4.w, n4.w);
#undef PACK
    ((uint4*)packed)[q] = o;
}

__global__ void __launch_bounds__(1024)
hist_p(const u32* __restrict__ packed, float* __restrict__ rep) {
    __shared__ float hist[NPP];
    const int i    = blockIdx.x;
    const int r    = i & 7;
    const int p    = (i >> 3) & 7;
    const int b    = r | ((i >> 6) << 3);
    const int base = p * NPP;

    for (int j = threadIdx.x; j < NPP / 4; j += 1024)
        ((f4*)hist)[j] = (f4){0.f, 0.f, 0.f, 0.f};
    __syncthreads();

    const int lo = b * QPS;
#define EDGE(W)                                                          \
        {                                                                \
            const u32 rel = ((W) >> 15) - (u32)base;                     \
            if (rel < (u32)NPP)                                          \
                atomicAdd(&hist[rel],                                    \
                          __uint_as_float(((W) & 0x7FFFu) << 16));       \
        }
    for (int q = lo + (int)threadIdx.x; q < lo + QPS; q += 1024) {
        const uint4 a = ((const uint4*)packed)[q];
        EDGE(a.x) EDGE(a.y) EDGE(a.z) EDGE(a.w)
    }
#undef EDGE
    __syncthreads();

    float* dst = rep + (size_t)b * NUM_NODES + base;
    for (int j = threadIdx.x; j < NPP / 4; j += 1024) {
        const f4 v = ((const f4*)hist)[j];
        __builtin_nontemporal_store(v, &((f4*)dst)[j]);
    }
}

#define RED_BLK 98
__global__ void __launch_bounds__(256)
gemv_reduce(const float* __restrict__ rep, float* __restrict__ nbr_sum,
            const float* __restrict__ x, const float* __restrict__ theta,
            float* __restrict__ h) {
    if (blockIdx.x < RED_BLK) {
        const int i = blockIdx.x * 256 + threadIdx.x;
        if (i >= NUM_NODES / 4) return;
        float4 a = make_float4(0.f, 0.f, 0.f, 0.f);
        #pragma unroll 8
        for (int r = 0; r < NSLICE; ++r) {
            const float4 v = ((const float4*)(rep + (size_t)r * NUM_NODES))[i];
            a.x += v.x; a.y += v.y; a.z += v.z; a.w += v.w;
        }
        float4 o;
        o.x = a.x > 0.f ? a.x : 1.0f;
        o.y = a.y > 0.f ? a.y : 1.0f;
        o.z = a.z > 0.f ? a.z : 1.0f;
        o.w = a.w > 0.f ? a.w : 1.0f;
        ((float4*)nbr_sum)[i] = o;
    } else {
        const int gb   = blockIdx.x - RED_BLK;
        const int lane = threadIdx.x & 63;
        const int wave = threadIdx.x >> 6;
        const float4 tw = *reinterpret_cast<const float4*>(&theta[lane * 4]);
        for (int row = gb * 4 + wave; row < NUM_NODES; row += 2048 * 4) {
            const float4 xv =
                *reinterpret_cast<const float4*>(&x[(size_t)row * INPUT_DIM + lane * 4]);
            float d = xv.x * tw.x + xv.y * tw.y + xv.z * tw.z + xv.w * tw.w;
            #pragma unroll
            for (int off = 32; off >= 1; off >>= 1)
                d += __shfl_xor(d, off);
            if (lane == 0) h[row] = d;
        }
    }
}

__global__ void __launch_bounds__(256)
bag_final(const int* __restrict__ bags, const float* __restrict__ alpha,
          const float* __restrict__ h, const float* __restrict__ ns,
          float* __restrict__ out) {
    const int bag  = blockIdx.x * 4 + (threadIdx.x >> 6);
    const int lane = threadIdx.x & 63;
    const int idx  = bags[bag * BAG_SIZE + lane];
    float v = h[idx] * ns[idx] * alpha[bag * BAG_SIZE + lane];
    #pragma unroll
    for (int off = 32; off >= 1; off >>= 1)
        v += __shfl_xor(v, off);
    if (lane == 0) out[bag] = v;
}

extern "C" void kernel_launch(void* const* d_in, const int* in_sizes, int n_in,
                              void* d_out, int out_size, void* d_ws, size_t ws_size,
                              hipStream_t stream) {
    const float* x            = (const float*)d_in[0];
    const int*   bags         = (const int*)d_in[1];
    const float* alpha        = (const float*)d_in[2];
    const int*   edge_src     = (const int*)d_in[3];
    const int*   edge_nbr     = (const int*)d_in[4];
    const float* node_weights = (const float*)d_in[5];
    const float* theta        = (const float*)d_in[6];
    float*       out          = (float*)d_out;

    // ws: packed[3.2M] u32 | rep[32][100000] f32 | nbr_sum | h
    u32*   packed  = (u32*)d_ws;
    float* rep     = (float*)d_ws + N_EDGES;
    float* nbr_sum = rep + (size_t)NSLICE * NUM_NODES;
    float* h       = nbr_sum + NUM_NODES;

    void* args[] = {(void*)&edge_src, (void*)&edge_nbr, (void*)&node_weights,
                    (void*)&bags, (void*)&alpha, (void*)&x, (void*)&theta,
                    (void*)&packed, (void*)&rep, (void*)&nbr_sum, (void*)&h,
                    (void*)&out};
    const hipError_t rc = hipLaunchCooperativeKernel(
        (const void*)fused_all, dim3(NBLK), dim3(1024), args, 0, stream);

    if (rc != hipSuccess) {
        // Fallback: proven R13 5-kernel pipeline.
        pack_edges<<<NQUAD / 256, 256, 0, stream>>>(edge_src, edge_nbr,
                                                    node_weights, packed);
        hist_p<<<P_PART * NSLICE, 1024, 0, stream>>>(packed, rep);
        gemv_reduce<<<RED_BLK + 2048, 256, 0, stream>>>(rep, nbr_sum, x, theta, h);
        bag_final<<<NUM_BAGS / 4, 256, 0, stream>>>(bags, alpha, h, nbr_sum, out);
    }
}

// Round 21
// 66.237 us; speedup vs baseline: 2.6394x; 2.6394x over previous
//
#include <hip/hip_runtime.h>

#define NUM_NODES 100000
#define INPUT_DIM 256
#define NUM_BAGS  2048
#define BAG_SIZE  64
#define N_EDGES   3200000
#define NQUAD     (N_EDGES / 4)   // 800000
#define P_PART    8
#define NPP       12500           // 50 KB static LDS
#define NSLICE    32
#define QPS       (NQUAD / NSLICE)   // 25000

typedef unsigned int u32;
typedef unsigned short u16;
typedef float f4 __attribute__((ext_vector_type(4)));
typedef u32   u2 __attribute__((ext_vector_type(2)));

// Pass A: pack (src, w) into one u32 per edge.
//   word = (src << 15) | bf15(nw[nbr])   (weights in [0,1) -> sign bit 0)
__global__ void __launch_bounds__(256)
pack_edges(const int* __restrict__ edge_src, const int* __restrict__ edge_nbr,
           const float* __restrict__ nw, u32* __restrict__ packed) {
    const int q = blockIdx.x * 256 + threadIdx.x;
    const int4 s4 = ((const int4*)edge_src)[q];
    const int4 n4 = ((const int4*)edge_nbr)[q];
#define PACK(S, N)  (((u32)(S) << 15) |                                     \
                     (((__float_as_uint(nw[(N)]) + 0x8000u) >> 16) & 0x7FFFu))
    uint4 o;
    o.x = PACK(s4.x, n4.x);
    o.y = PACK(s4.y, n4.y);
    o.z = PACK(s4.z, n4.z);
    o.w = PACK(s4.w, n4.w);
#undef PACK
    ((uint4*)packed)[q] = o;
}

// Pass B: P=8 partitioned LDS histogram (R13 structure; measured 20.7 us).
// ONLY change vs R13: flush rep as bf16 (uint2 of 4 bf16; 8B-aligned for all
// partitions) -> flush bytes halve 12.8 -> 6.4 MB.
__global__ void __launch_bounds__(1024)
hist_p(const u32* __restrict__ packed, u16* __restrict__ rep16) {
    __shared__ float hist[NPP];
    const int i    = blockIdx.x;
    const int r    = i & 7;
    const int p    = (i >> 3) & 7;
    const int b    = r | ((i >> 6) << 3);      // 0..31
    const int base = p * NPP;

    for (int j = threadIdx.x; j < NPP / 4; j += 1024)
        ((f4*)hist)[j] = (f4){0.f, 0.f, 0.f, 0.f};
    __syncthreads();

    const int lo = b * QPS;
#define EDGE(W)                                                          \
        {                                                                \
            const u32 rel = ((W) >> 15) - (u32)base;                     \
            if (rel < (u32)NPP)                                          \
                atomicAdd(&hist[rel],                                    \
                          __uint_as_float(((W) & 0x7FFFu) << 16));       \
        }
    for (int q = lo + (int)threadIdx.x; q < lo + QPS; q += 1024) {
        const uint4 a = ((const uint4*)packed)[q];
        EDGE(a.x) EDGE(a.y) EDGE(a.z) EDGE(a.w)
    }
#undef EDGE
    __syncthreads();

    // bf16 flush: 4 nodes per uint2 NT store (sums >= 0, sign bit 0).
    u16* dst = rep16 + (size_t)b * NUM_NODES + base;
    for (int j = threadIdx.x; j < NPP / 4; j += 1024) {
        const u32 b0 = (__float_as_uint(hist[4 * j + 0]) + 0x8000u) >> 16;
        const u32 b1 = (__float_as_uint(hist[4 * j + 1]) + 0x8000u) >> 16;
        const u32 b2 = (__float_as_uint(hist[4 * j + 2]) + 0x8000u) >> 16;
        const u32 b3 = (__float_as_uint(hist[4 * j + 3]) + 0x8000u) >> 16;
        u2 v;
        v.x = b0 | (b1 << 16);
        v.y = b2 | (b3 << 16);
        __builtin_nontemporal_store(v, (u2*)dst + j);
    }
}

// Fused: blocks [0,RED_BLK) reduce bf16 rep -> nbr_sum (f32, with >0?:1.0
// fold); blocks [RED_BLK,..) dense GEMV. Reduce read halves: 12.8 -> 6.4 MB.
#define RED_BLK 98   // ceil(25000 4-node-groups / 256)
__global__ void __launch_bounds__(256)
gemv_reduce(const u16* __restrict__ rep16, float* __restrict__ nbr_sum,
            const float* __restrict__ x, const float* __restrict__ theta,
            float* __restrict__ h) {
    if (blockIdx.x < RED_BLK) {
        const int i = blockIdx.x * 256 + threadIdx.x;   // 4-node group
        if (i >= NUM_NODES / 4) return;
        float a0 = 0.f, a1 = 0.f, a2 = 0.f, a3 = 0.f;
        #pragma unroll 8
        for (int r = 0; r < NSLICE; ++r) {
            const u2 v = ((const u2*)(rep16 + (size_t)r * NUM_NODES))[i];
            a0 += __uint_as_float(v.x << 16);
            a1 += __uint_as_float(v.x & 0xFFFF0000u);
            a2 += __uint_as_float(v.y << 16);
            a3 += __uint_as_float(v.y & 0xFFFF0000u);
        }
        float4 o;
        o.x = a0 > 0.f ? a0 : 1.0f;
        o.y = a1 > 0.f ? a1 : 1.0f;
        o.z = a2 > 0.f ? a2 : 1.0f;
        o.w = a3 > 0.f ? a3 : 1.0f;
        ((float4*)nbr_sum)[i] = o;
    } else {
        const int gb   = blockIdx.x - RED_BLK;
        const int lane = threadIdx.x & 63;
        const int wave = threadIdx.x >> 6;
        const float4 tw = *reinterpret_cast<const float4*>(&theta[lane * 4]);
        for (int row = gb * 4 + wave; row < NUM_NODES; row += 2048 * 4) {
            const float4 xv =
                *reinterpret_cast<const float4*>(&x[(size_t)row * INPUT_DIM + lane * 4]);
            float d = xv.x * tw.x + xv.y * tw.y + xv.z * tw.z + xv.w * tw.w;
            #pragma unroll
            for (int off = 32; off >= 1; off >>= 1)
                d += __shfl_xor(d, off);
            if (lane == 0) h[row] = d;
        }
    }
}

// Final: out[bag] = sum_item h[idx] * nbr_sum[idx] * alpha
__global__ void __launch_bounds__(256)
bag_final(const int* __restrict__ bags, const float* __restrict__ alpha,
          const float* __restrict__ h, const float* __restrict__ ns,
          float* __restrict__ out) {
    const int bag  = blockIdx.x * 4 + (threadIdx.x >> 6);
    const int lane = threadIdx.x & 63;
    const int idx  = bags[bag * BAG_SIZE + lane];
    float v = h[idx] * ns[idx] * alpha[bag * BAG_SIZE + lane];
    #pragma unroll
    for (int off = 32; off >= 1; off >>= 1)
        v += __shfl_xor(v, off);
    if (lane == 0) out[bag] = v;
}

// Tiny-ws fallback.
__global__ void __launch_bounds__(256)
edge_atomic(const int* __restrict__ edge_src, const int* __restrict__ edge_nbr,
            const float* __restrict__ nw, float* __restrict__ nbr_sum) {
    const int t = blockIdx.x * blockDim.x + threadIdx.x;
    const int4 s4 = ((const int4*)edge_src)[t];
    const int4 n4 = ((const int4*)edge_nbr)[t];
    atomicAdd(&nbr_sum[s4.x], nw[n4.x]);
    atomicAdd(&nbr_sum[s4.y], nw[n4.y]);
    atomicAdd(&nbr_sum[s4.z], nw[n4.z]);
    atomicAdd(&nbr_sum[s4.w], nw[n4.w]);
}

__global__ void __launch_bounds__(256)
fixup_nosum(float* __restrict__ nbr_sum) {
    const int i = blockIdx.x * 256 + threadIdx.x;
    if (i < NUM_NODES && nbr_sum[i] == 0.f) nbr_sum[i] = 1.0f;
}

__global__ void __launch_bounds__(256)
gemv_h(const float* __restrict__ x, const float* __restrict__ theta,
       float* __restrict__ h) {
    const int lane = threadIdx.x & 63;
    const int wave = threadIdx.x >> 6;
    const float4 tw = *reinterpret_cast<const float4*>(&theta[lane * 4]);
    const int stride = gridDim.x * 4;
    for (int row = blockIdx.x * 4 + wave; row < NUM_NODES; row += stride) {
        const float4 xv =
            *reinterpret_cast<const float4*>(&x[(size_t)row * INPUT_DIM + lane * 4]);
        float d = xv.x * tw.x + xv.y * tw.y + xv.z * tw.z + xv.w * tw.w;
        #pragma unroll
        for (int off = 32; off >= 1; off >>= 1)
            d += __shfl_xor(d, off);
        if (lane == 0) h[row] = d;
    }
}

extern "C" void kernel_launch(void* const* d_in, const int* in_sizes, int n_in,
                              void* d_out, int out_size, void* d_ws, size_t ws_size,
                              hipStream_t stream) {
    const float* x            = (const float*)d_in[0];
    const int*   bags         = (const int*)d_in[1];
    const float* alpha        = (const float*)d_in[2];
    const int*   edge_src     = (const int*)d_in[3];
    const int*   edge_nbr     = (const int*)d_in[4];
    const float* node_weights = (const float*)d_in[5];
    const float* theta        = (const float*)d_in[6];
    float*       out          = (float*)d_out;

    // ws: packed[3.2M] u32 | rep16[32][100000] u16 | nbr_sum f32 | h f32
    const size_t need_full = (size_t)N_EDGES * 4
                           + (size_t)NSLICE * NUM_NODES * 2
                           + 2 * (size_t)NUM_NODES * 4;

    if (ws_size >= need_full) {
        u32*   packed  = (u32*)d_ws;
        u16*   rep16   = (u16*)(packed + N_EDGES);
        float* nbr_sum = (float*)(rep16 + (size_t)NSLICE * NUM_NODES);
        float* h       = nbr_sum + NUM_NODES;

        pack_edges<<<NQUAD / 256, 256, 0, stream>>>(edge_src, edge_nbr,
                                                    node_weights, packed);
        hist_p<<<P_PART * NSLICE, 1024, 0, stream>>>(packed, rep16);
        gemv_reduce<<<RED_BLK + 2048, 256, 0, stream>>>(rep16, nbr_sum, x,
                                                        theta, h);
        bag_final<<<NUM_BAGS / 4, 256, 0, stream>>>(bags, alpha, h, nbr_sum, out);
    } else {
        float* nbr_sum = (float*)d_ws;
        float* h       = nbr_sum + NUM_NODES;
        hipMemsetAsync(nbr_sum, 0, (size_t)NUM_NODES * 4, stream);
        edge_atomic<<<(N_EDGES / 4) / 256, 256, 0, stream>>>(
            edge_src, edge_nbr, node_weights, nbr_sum);
        fixup_nosum<<<(NUM_NODES + 255) / 256, 256, 0, stream>>>(nbr_sum);
        gemv_h<<<2048, 256, 0, stream>>>(x, theta, h);
        bag_final<<<NUM_BAGS / 4, 256, 0, stream>>>(bags, alpha, h, nbr_sum, out);
    }
}

// Round 22
// 66.201 us; speedup vs baseline: 2.6408x; 1.0005x over previous
//
#include <hip/hip_runtime.h>

#define NUM_NODES 100000
#define INPUT_DIM 256
#define NUM_BAGS  2048
#define BAG_SIZE  64
#define N_EDGES   3200000
#define NQUAD     (N_EDGES / 4)   // 800000
#define P_PART    8
#define NPP       12500           // 50 KB static LDS
#define NSLICE    32
#define QPS       (NQUAD / NSLICE)   // 25000
#define PACK_BLK  (NQUAD / 256)      // 3125
#define GEMV_BLK  2048

typedef unsigned int u32;
typedef unsigned short u16;
typedef float f4 __attribute__((ext_vector_type(4)));
typedef u32   u2 __attribute__((ext_vector_type(2)));

// K1: pack || gemv — two INDEPENDENT streaming phases, block-range split.
// Blocks [0,PACK_BLK): word = (src<<15)|bf15(nw[nbr]) (weights in [0,1)).
// Blocks [PACK_BLK, PACK_BLK+GEMV_BLK): h[n] = theta . x[n].
__global__ void __launch_bounds__(256)
pack_gemv(const int* __restrict__ edge_src, const int* __restrict__ edge_nbr,
          const float* __restrict__ nw, u32* __restrict__ packed,
          const float* __restrict__ x, const float* __restrict__ theta,
          float* __restrict__ h) {
    if (blockIdx.x < PACK_BLK) {
        const int q = blockIdx.x * 256 + threadIdx.x;
        const int4 s4 = ((const int4*)edge_src)[q];
        const int4 n4 = ((const int4*)edge_nbr)[q];
#define PACK(S, N)  (((u32)(S) << 15) |                                     \
                     (((__float_as_uint(nw[(N)]) + 0x8000u) >> 16) & 0x7FFFu))
        uint4 o;
        o.x = PACK(s4.x, n4.x);
        o.y = PACK(s4.y, n4.y);
        o.z = PACK(s4.z, n4.z);
        o.w = PACK(s4.w, n4.w);
#undef PACK
        ((uint4*)packed)[q] = o;
    } else {
        const int gb   = blockIdx.x - PACK_BLK;        // 0..2047
        const int lane = threadIdx.x & 63;
        const int wave = threadIdx.x >> 6;
        const float4 tw = *reinterpret_cast<const float4*>(&theta[lane * 4]);
        for (int row = gb * 4 + wave; row < NUM_NODES; row += GEMV_BLK * 4) {
            const float4 xv =
                *reinterpret_cast<const float4*>(&x[(size_t)row * INPUT_DIM + lane * 4]);
            float d = xv.x * tw.x + xv.y * tw.y + xv.z * tw.z + xv.w * tw.w;
            #pragma unroll
            for (int off = 32; off >= 1; off >>= 1)
                d += __shfl_xor(d, off);
            if (lane == 0) h[row] = d;
        }
    }
}

// K2: P=8 partitioned LDS histogram, bf16 flush (R21 exact).
__global__ void __launch_bounds__(1024)
hist_p(const u32* __restrict__ packed, u16* __restrict__ rep16) {
    __shared__ float hist[NPP];
    const int i    = blockIdx.x;
    const int r    = i & 7;
    const int p    = (i >> 3) & 7;
    const int b    = r | ((i >> 6) << 3);      // 0..31
    const int base = p * NPP;

    for (int j = threadIdx.x; j < NPP / 4; j += 1024)
        ((f4*)hist)[j] = (f4){0.f, 0.f, 0.f, 0.f};
    __syncthreads();

    const int lo = b * QPS;
#define EDGE(W)                                                          \
        {                                                                \
            const u32 rel = ((W) >> 15) - (u32)base;                     \
            if (rel < (u32)NPP)                                          \
                atomicAdd(&hist[rel],                                    \
                          __uint_as_float(((W) & 0x7FFFu) << 16));       \
        }
    for (int q = lo + (int)threadIdx.x; q < lo + QPS; q += 1024) {
        const uint4 a = ((const uint4*)packed)[q];
        EDGE(a.x) EDGE(a.y) EDGE(a.z) EDGE(a.w)
    }
#undef EDGE
    __syncthreads();

    u16* dst = rep16 + (size_t)b * NUM_NODES + base;
    for (int j = threadIdx.x; j < NPP / 4; j += 1024) {
        const u32 b0 = (__float_as_uint(hist[4 * j + 0]) + 0x8000u) >> 16;
        const u32 b1 = (__float_as_uint(hist[4 * j + 1]) + 0x8000u) >> 16;
        const u32 b2 = (__float_as_uint(hist[4 * j + 2]) + 0x8000u) >> 16;
        const u32 b3 = (__float_as_uint(hist[4 * j + 3]) + 0x8000u) >> 16;
        u2 v;
        v.x = b0 | (b1 << 16);
        v.y = b2 | (b3 << 16);
        __builtin_nontemporal_store(v, (u2*)dst + j);
    }
}

// K3: reduce bf16 rep -> nbr_sum (f32), fold (sum>0 ? sum : 1.0).
__global__ void __launch_bounds__(256)
reduce_rep(const u16* __restrict__ rep16, float* __restrict__ nbr_sum) {
    const int i = blockIdx.x * 256 + threadIdx.x;   // 4-node group
    if (i >= NUM_NODES / 4) return;
    float a0 = 0.f, a1 = 0.f, a2 = 0.f, a3 = 0.f;
    #pragma unroll 8
    for (int r = 0; r < NSLICE; ++r) {
        const u2 v = ((const u2*)(rep16 + (size_t)r * NUM_NODES))[i];
        a0 += __uint_as_float(v.x << 16);
        a1 += __uint_as_float(v.x & 0xFFFF0000u);
        a2 += __uint_as_float(v.y << 16);
        a3 += __uint_as_float(v.y & 0xFFFF0000u);
    }
    float4 o;
    o.x = a0 > 0.f ? a0 : 1.0f;
    o.y = a1 > 0.f ? a1 : 1.0f;
    o.z = a2 > 0.f ? a2 : 1.0f;
    o.w = a3 > 0.f ? a3 : 1.0f;
    ((float4*)nbr_sum)[i] = o;
}

// K4: out[bag] = sum_item h[idx] * nbr_sum[idx] * alpha
__global__ void __launch_bounds__(256)
bag_final(const int* __restrict__ bags, const float* __restrict__ alpha,
          const float* __restrict__ h, const float* __restrict__ ns,
          float* __restrict__ out) {
    const int bag  = blockIdx.x * 4 + (threadIdx.x >> 6);
    const int lane = threadIdx.x & 63;
    const int idx  = bags[bag * BAG_SIZE + lane];
    float v = h[idx] * ns[idx] * alpha[bag * BAG_SIZE + lane];
    #pragma unroll
    for (int off = 32; off >= 1; off >>= 1)
        v += __shfl_xor(v, off);
    if (lane == 0) out[bag] = v;
}

// Tiny-ws fallback.
__global__ void __launch_bounds__(256)
edge_atomic(const int* __restrict__ edge_src, const int* __restrict__ edge_nbr,
            const float* __restrict__ nw, float* __restrict__ nbr_sum) {
    const int t = blockIdx.x * blockDim.x + threadIdx.x;
    const int4 s4 = ((const int4*)edge_src)[t];
    const int4 n4 = ((const int4*)edge_nbr)[t];
    atomicAdd(&nbr_sum[s4.x], nw[n4.x]);
    atomicAdd(&nbr_sum[s4.y], nw[n4.y]);
    atomicAdd(&nbr_sum[s4.z], nw[n4.z]);
    atomicAdd(&nbr_sum[s4.w], nw[n4.w]);
}

__global__ void __launch_bounds__(256)
fixup_nosum(float* __restrict__ nbr_sum) {
    const int i = blockIdx.x * 256 + threadIdx.x;
    if (i < NUM_NODES && nbr_sum[i] == 0.f) nbr_sum[i] = 1.0f;
}

__global__ void __launch_bounds__(256)
gemv_h(const float* __restrict__ x, const float* __restrict__ theta,
       float* __restrict__ h) {
    const int lane = threadIdx.x & 63;
    const int wave = threadIdx.x >> 6;
    const float4 tw = *reinterpret_cast<const float4*>(&theta[lane * 4]);
    const int stride = gridDim.x * 4;
    for (int row = blockIdx.x * 4 + wave; row < NUM_NODES; row += stride) {
        const float4 xv =
            *reinterpret_cast<const float4*>(&x[(size_t)row * INPUT_DIM + lane * 4]);
        float d = xv.x * tw.x + xv.y * tw.y + xv.z * tw.z + xv.w * tw.w;
        #pragma unroll
        for (int off = 32; off >= 1; off >>= 1)
            d += __shfl_xor(d, off);
        if (lane == 0) h[row] = d;
    }
}

extern "C" void kernel_launch(void* const* d_in, const int* in_sizes, int n_in,
                              void* d_out, int out_size, void* d_ws, size_t ws_size,
                              hipStream_t stream) {
    const float* x            = (const float*)d_in[0];
    const int*   bags         = (const int*)d_in[1];
    const float* alpha        = (const float*)d_in[2];
    const int*   edge_src     = (const int*)d_in[3];
    const int*   edge_nbr     = (const int*)d_in[4];
    const float* node_weights = (const float*)d_in[5];
    const float* theta        = (const float*)d_in[6];
    float*       out          = (float*)d_out;

    // ws: packed[3.2M] u32 | rep16[32][100000] u16 | nbr_sum f32 | h f32
    const size_t need_full = (size_t)N_EDGES * 4
                           + (size_t)NSLICE * NUM_NODES * 2
                           + 2 * (size_t)NUM_NODES * 4;

    if (ws_size >= need_full) {
        u32*   packed  = (u32*)d_ws;
        u16*   rep16   = (u16*)(packed + N_EDGES);
        float* nbr_sum = (float*)(rep16 + (size_t)NSLICE * NUM_NODES);
        float* h       = nbr_sum + NUM_NODES;

        pack_gemv<<<PACK_BLK + GEMV_BLK, 256, 0, stream>>>(
            edge_src, edge_nbr, node_weights, packed, x, theta, h);
        hist_p<<<P_PART * NSLICE, 1024, 0, stream>>>(packed, rep16);
        reduce_rep<<<(NUM_NODES / 4 + 255) / 256, 256, 0, stream>>>(rep16,
                                                                    nbr_sum);
        bag_final<<<NUM_BAGS / 4, 256, 0, stream>>>(bags, alpha, h, nbr_sum, out);
    } else {
        float* nbr_sum = (float*)d_ws;
        float* h       = nbr_sum + NUM_NODES;
        hipMemsetAsync(nbr_sum, 0, (size_t)NUM_NODES * 4, stream);
        edge_atomic<<<(N_EDGES / 4) / 256, 256, 0, stream>>>(
            edge_src, edge_nbr, node_weights, nbr_sum);
        fixup_nosum<<<(NUM_NODES + 255) / 256, 256, 0, stream>>>(nbr_sum);
        gemv_h<<<2048, 256, 0, stream>>>(x, theta, h);
        bag_final<<<NUM_BAGS / 4, 256, 0, stream>>>(bags, alpha, h, nbr_sum, out);
    }
}